// Round 8
// baseline (202.136 us; speedup 1.0000x reference)
//
#include <hip/hip_runtime.h>
#include <hip/hip_bf16.h>

// Problem constants
#define Bn 16
#define Tn 2048
#define Hn 256
#define Pn 256
#define Ln 32              // scan chunk length
#define NCn (Tn / Ln)      // 64 chunks
#define BTn (Bn * Tn)      // 32768 rows
#define NB  (2 * Pn)       // 512: bu row length in floats (re/im interleaved)

// MFMA GEMM tiling (k_bu)
#define BM 128
#define BK 32
#define APAD 40            // padded LDS row (bf16 elems)
#define YPAD 8             // pad for fused-kernel xs tile

typedef __attribute__((ext_vector_type(8))) short short8;
typedef __attribute__((ext_vector_type(4))) float f32x4;

__device__ __forceinline__ unsigned short f2bf(float f) {
  unsigned u = __float_as_uint(f);
  return (unsigned short)((u + 0x7FFFu + ((u >> 16) & 1u)) >> 16);  // RNE
}

__device__ __forceinline__ float2 cmul(float2 a, float2 b) {
  return make_float2(fmaf(a.x, b.x, -(a.y * b.y)), fmaf(a.x, b.y, a.y * b.x));
}

// ---------------------------------------------------------------------------
// k_prep: lam_bar[p]; b_bfT[n=2p|2p+1][h] = bf16(Re/Im b_bar[p][h]);
//         c_bfT[h][n=2p|2p+1] = bf16(cr[h][p] / -ci[h][p])
// ---------------------------------------------------------------------------
__global__ void k_prep(const float* __restrict__ lam_re,
                       const float* __restrict__ lam_im,
                       const float* __restrict__ log_step,
                       const float* __restrict__ b_in,   // (P,H,2)
                       const float* __restrict__ c_in,   // (H,P,2)
                       float2* __restrict__ lam_bar,     // [P]
                       unsigned short* __restrict__ b_bfT, // [512][256]
                       unsigned short* __restrict__ c_bfT) { // [256][512]
  const int blk = blockIdx.x;   // h for b-part, p for c-part
  const int tid = threadIdx.x;  // p for b-part, h for c-part

  float s = expf(log_step[tid]);
  float re = lam_re[tid], im = lam_im[tid];
  float er = expf(re * s);
  float sn, cs;
  sincosf(im * s, &sn, &cs);
  float2 lb = make_float2(er * cs, er * sn);
  if (blk == 0) lam_bar[tid] = lb;

  float denom = re * re + im * im;
  float nx = lb.x - 1.0f, ny = lb.y;
  float2 coef = make_float2((nx * re + ny * im) / denom,
                            (ny * re - nx * im) / denom);

  // b-part: h=blk, p=tid
  float2 bt = make_float2(b_in[(tid * Hn + blk) * 2 + 0],
                          b_in[(tid * Hn + blk) * 2 + 1]);
  float2 bb = cmul(coef, bt);
  b_bfT[(size_t)(2 * tid + 0) * Hn + blk] = f2bf(bb.x);
  b_bfT[(size_t)(2 * tid + 1) * Hn + blk] = f2bf(bb.y);

  // c-part: p=blk, h=tid
  float cr = c_in[(tid * Pn + blk) * 2 + 0];
  float ci = c_in[(tid * Pn + blk) * 2 + 1];
  c_bfT[(size_t)tid * NB + 2 * blk + 0] = f2bf(cr);
  c_bfT[(size_t)tid * NB + 2 * blk + 1] = f2bf(-ci);
}

// ---------------------------------------------------------------------------
// k_bu_mfma: bu[bt][n] = sum_h u[bt][h] * B[h][n]  (validated round 6)
// ---------------------------------------------------------------------------
__launch_bounds__(256)
__global__ void k_bu_mfma(const float* __restrict__ u,            // [BTn][Hn]
                          const unsigned short* __restrict__ bT,  // [NB][Hn]
                          float* __restrict__ bu) {               // [BTn][NB]
  __shared__ unsigned short sA[BM * APAD];
  __shared__ unsigned short sB[BM * APAD];
  const int tid = threadIdx.x;
  const int bm = blockIdx.x, bn = blockIdx.y;
  const int lane = tid & 63, wid = tid >> 6;
  const int wr = wid >> 1, wc = wid & 1;
  const int grp = lane >> 4, l15 = lane & 15;

  const f32x4 vzero = {0.f, 0.f, 0.f, 0.f};
  f32x4 acc[4][4];
#pragma unroll
  for (int i = 0; i < 4; i++)
#pragma unroll
    for (int j = 0; j < 4; j++) acc[i][j] = vzero;

  const int sr = tid >> 1, sseg = (tid & 1) * 16;
  const float* uRow = u + (size_t)(bm * BM + sr) * Hn + sseg;
  const unsigned short* bRow = bT + (size_t)(bn * BM + sr) * Hn + sseg;
  unsigned short* sAw = &sA[sr * APAD + sseg];
  unsigned short* sBw = &sB[sr * APAD + sseg];

  for (int k0 = 0; k0 < Hn; k0 += BK) {
    float4 v0 = *reinterpret_cast<const float4*>(uRow + k0);
    float4 v1 = *reinterpret_cast<const float4*>(uRow + k0 + 4);
    float4 v2 = *reinterpret_cast<const float4*>(uRow + k0 + 8);
    float4 v3 = *reinterpret_cast<const float4*>(uRow + k0 + 12);
    short8 q0 = *reinterpret_cast<const short8*>(bRow + k0);
    short8 q1 = *reinterpret_cast<const short8*>(bRow + k0 + 8);
    short8 p0, p1;
    p0[0] = (short)f2bf(v0.x); p0[1] = (short)f2bf(v0.y);
    p0[2] = (short)f2bf(v0.z); p0[3] = (short)f2bf(v0.w);
    p0[4] = (short)f2bf(v1.x); p0[5] = (short)f2bf(v1.y);
    p0[6] = (short)f2bf(v1.z); p0[7] = (short)f2bf(v1.w);
    p1[0] = (short)f2bf(v2.x); p1[1] = (short)f2bf(v2.y);
    p1[2] = (short)f2bf(v2.z); p1[3] = (short)f2bf(v2.w);
    p1[4] = (short)f2bf(v3.x); p1[5] = (short)f2bf(v3.y);
    p1[6] = (short)f2bf(v3.z); p1[7] = (short)f2bf(v3.w);
    *reinterpret_cast<short8*>(sAw) = p0;
    *reinterpret_cast<short8*>(sAw + 8) = p1;
    *reinterpret_cast<short8*>(sBw) = q0;
    *reinterpret_cast<short8*>(sBw + 8) = q1;
    __syncthreads();

    short8 af[4], bfr[4];
#pragma unroll
    for (int i = 0; i < 4; i++)
      af[i] = *reinterpret_cast<const short8*>(
          &sA[(wr * 64 + i * 16 + l15) * APAD + grp * 8]);
#pragma unroll
    for (int j = 0; j < 4; j++)
      bfr[j] = *reinterpret_cast<const short8*>(
          &sB[(wc * 64 + j * 16 + l15) * APAD + grp * 8]);
#pragma unroll
    for (int i = 0; i < 4; i++)
#pragma unroll
      for (int j = 0; j < 4; j++)
        acc[i][j] = __builtin_amdgcn_mfma_f32_16x16x32_bf16(af[i], bfr[j],
                                                            acc[i][j], 0, 0, 0);
    __syncthreads();
  }

  const int r0 = bm * BM + wr * 64 + grp * 4;
  const int c0 = bn * BM + wc * 64 + l15;
#pragma unroll
  for (int i = 0; i < 4; i++)
#pragma unroll
    for (int j = 0; j < 4; j++) {
#pragma unroll
      for (int r = 0; r < 4; r++)
        bu[(size_t)(r0 + i * 16 + r) * NB + (c0 + j * 16)] = acc[i][j][r];
    }
}

// ---------------------------------------------------------------------------
// k_sum: per-(b,chunk,p) scan summary (A,B,C). Grid (NCn,Bn), 256 thr.
// ---------------------------------------------------------------------------
__launch_bounds__(256)
__global__ void k_sum(const float2* __restrict__ bu,      // [BTn][Pn] complex
                      const int* __restrict__ mask,       // (B,T)
                      const float2* __restrict__ lam_bar, // [P]
                      float4* __restrict__ sumAB,         // (B,NC,P)
                      float* __restrict__ sumC) {         // (B,NC,P)
  const int chunk = blockIdx.x, b = blockIdx.y, p = threadIdx.x;
  const float2 lam = lam_bar[p];
  const float2* buB = bu + (size_t)(b * Tn + chunk * Ln) * Pn;
  const int* mB = mask + b * Tn + chunk * Ln;

  float2 A = make_float2(1.f, 0.f), Bv = make_float2(0.f, 0.f);
  float C = 0.f;
  for (int t = 0; t < Ln; t++) {
    int m = mB[t];
    float2 v = buB[t * Pn + p];
    float2 nA = cmul(lam, A);
    float2 nB = cmul(lam, Bv);
    nB.x += v.x; nB.y += v.y;
    A = m ? lam : nA;
    Bv = m ? v : nB;
    C = m ? 1.f : C;
  }
  size_t o = ((size_t)(b * NCn + chunk)) * Pn + p;
  sumAB[o] = make_float4(A.x, A.y, Bv.x, Bv.y);
  sumC[o] = C;
}

// ---------------------------------------------------------------------------
// k_scan: inter-chunk scan. grid = B blocks, 256 threads (p).
// ---------------------------------------------------------------------------
__global__ void k_scan(const float* __restrict__ carry_re,
                       const float* __restrict__ carry_im,
                       const float4* __restrict__ sumAB,
                       const float* __restrict__ sumC,
                       float2* __restrict__ xe) {
  int b = blockIdx.x, p = threadIdx.x;
  float2 x = make_float2(carry_re[b * Pn + p], carry_im[b * Pn + p]);
  for (int k = 0; k < NCn; k++) {
    size_t o = ((size_t)(b * NCn + k)) * Pn + p;
    xe[o] = x;
    float4 ab = sumAB[o];
    float C = sumC[o];
    float2 nx = cmul(make_float2(ab.x, ab.y), x);
    nx.x += ab.z; nx.y += ab.w;
    x = (C != 0.f) ? make_float2(ab.z, ab.w) : nx;
  }
}

// ---------------------------------------------------------------------------
// k_apply_y: FUSED within-chunk scan + y-GEMM.
// Grid (NCn, Bn) = 1024 blocks, 256 thr (4 waves).
// Phase 1: thread p scans 32 t's, xs -> LDS as bf16 (re/im interleaved cols).
// Phase 2: y[t][h] = sum_k sXs[t][k]*C'[k][h] + d[h]*u[t][h]; M=32,N=256,K=512.
//   B-fragments read directly from global c_bfT (256 KB, L2-resident).
// ---------------------------------------------------------------------------
__launch_bounds__(256)
__global__ void k_apply_y(const int* __restrict__ mask,       // (B,T)
                          const float2* __restrict__ lam_bar, // [P]
                          const float2* __restrict__ xe,      // (B,NC,P)
                          const float2* __restrict__ bu,      // [BTn][Pn] cplx
                          const unsigned short* __restrict__ cT, // [Hn][NB]
                          const float* __restrict__ u,        // [BTn][Hn]
                          const float* __restrict__ dvec,     // [Hn]
                          float* __restrict__ y,              // [BTn][Hn]
                          float* __restrict__ out_xt,
                          int xt_interleaved) {
  __shared__ unsigned short sXs[Ln * (NB + YPAD)];  // 32 x 520 bf16 = 33.3 KB
  const int chunk = blockIdx.x, b = blockIdx.y;
  const int tid = threadIdx.x;
  const int t0 = chunk * Ln;

  // ---- Phase 1: within-chunk scan (thread = p) ----
  {
    const int p = tid;
    float2 x = xe[((size_t)(b * NCn + chunk)) * Pn + p];
    const float2 lam = lam_bar[p];
    const float2* buB = bu + (size_t)(b * Tn + t0) * Pn;
    const int* mB = mask + b * Tn + t0;

    for (int j0 = 0; j0 < Ln; j0 += 8) {
      float2 v[8];
      int m[8];
#pragma unroll
      for (int q = 0; q < 8; q++) {
        v[q] = buB[(j0 + q) * Pn + p];
        m[q] = mB[j0 + q];
      }
#pragma unroll
      for (int q = 0; q < 8; q++) {
        float2 nx = cmul(lam, x);
        nx.x += v[q].x; nx.y += v[q].y;
        x = m[q] ? v[q] : nx;
        unsigned pk = (unsigned)f2bf(x.x) | ((unsigned)f2bf(x.y) << 16);
        *reinterpret_cast<unsigned*>(&sXs[(j0 + q) * (NB + YPAD) + 2 * p]) = pk;
      }
    }
    if (chunk == NCn - 1) {
      if (xt_interleaved) {
        out_xt[(b * Pn + p) * 2 + 0] = x.x;
        out_xt[(b * Pn + p) * 2 + 1] = x.y;
      } else {
        out_xt[b * Pn + p] = x.x;
      }
    }
  }
  __syncthreads();

  // ---- Phase 2: y-GEMM. 4 waves split N; M=32 (2 frags), K=512 ----
  const int lane = tid & 63, w = tid >> 6;
  const int grp = lane >> 4, l15 = lane & 15;
  const int n0 = w * 64;

  const f32x4 vzero = {0.f, 0.f, 0.f, 0.f};
  f32x4 acc[2][4];
#pragma unroll
  for (int i = 0; i < 2; i++)
#pragma unroll
    for (int j = 0; j < 4; j++) acc[i][j] = vzero;

  for (int k0 = 0; k0 < NB; k0 += BK) {
    short8 af[2], bfr[4];
#pragma unroll
    for (int i = 0; i < 2; i++)
      af[i] = *reinterpret_cast<const short8*>(
          &sXs[(i * 16 + l15) * (NB + YPAD) + k0 + grp * 8]);
#pragma unroll
    for (int j = 0; j < 4; j++)
      bfr[j] = *reinterpret_cast<const short8*>(
          &cT[(size_t)(n0 + j * 16 + l15) * NB + k0 + grp * 8]);
#pragma unroll
    for (int i = 0; i < 2; i++)
#pragma unroll
      for (int j = 0; j < 4; j++)
        acc[i][j] = __builtin_amdgcn_mfma_f32_16x16x32_bf16(af[i], bfr[j],
                                                            acc[i][j], 0, 0, 0);
  }

  // epilogue: y = acc + d*u   (C/D map: col=lane&15, row=(lane>>4)*4+reg)
#pragma unroll
  for (int j = 0; j < 4; j++) {
    const int h = n0 + j * 16 + l15;
    const float dv = dvec[h];
#pragma unroll
    for (int i = 0; i < 2; i++) {
      const int tl0 = i * 16 + grp * 4;
#pragma unroll
      for (int r = 0; r < 4; r++) {
        const size_t row = (size_t)(b * Tn + t0 + tl0 + r);
        y[row * Hn + h] = fmaf(dv, u[row * Hn + h], acc[i][j][r]);
      }
    }
  }
}

// ---------------------------------------------------------------------------
extern "C" void kernel_launch(void* const* d_in, const int* in_sizes, int n_in,
                              void* d_out, int out_size, void* d_ws, size_t ws_size,
                              hipStream_t stream) {
  const float* inputs   = (const float*)d_in[0];  // (B,T,H)
  const int*   mask     = (const int*)d_in[1];    // (B,T)
  const float* carry_re = (const float*)d_in[2];  // (B,P)
  const float* carry_im = (const float*)d_in[3];  // (B,P)
  const float* lam_re   = (const float*)d_in[4];  // (P)
  const float* lam_im   = (const float*)d_in[5];  // (P)
  const float* b_in     = (const float*)d_in[6];  // (P,H,2)
  const float* c_in     = (const float*)d_in[7];  // (H,P,2)
  const float* d_vec    = (const float*)d_in[8];  // (H)
  const float* log_step = (const float*)d_in[9];  // (P)

  // Output layout (round-4 verified: real-only x_t, y at offset B*P).
  const int y_elems = Bn * Tn * Hn;
  const int xt_elems = out_size - y_elems;
  const int xt_interleaved = (xt_elems >= Bn * Pn * 2) ? 1 : 0;

  float* out = (float*)d_out;
  float* out_xt = out;
  float* out_y  = out + xt_elems;

  char* ws = (char*)d_ws;
  size_t off = 0;
  auto alloc = [&](size_t bytes) -> void* {
    void* ptr = ws + off;
    off += (bytes + 255) & ~(size_t)255;
    return ptr;
  };
  float* bu              = (float*)alloc((size_t)BTn * NB * sizeof(float)); // 64 MB
  unsigned short* b_bfT  = (unsigned short*)alloc((size_t)NB * Hn * sizeof(short));
  unsigned short* c_bfT  = (unsigned short*)alloc((size_t)Hn * NB * sizeof(short));
  float2* lam_bar        = (float2*)alloc(Pn * sizeof(float2));
  float4* sumAB          = (float4*)alloc((size_t)Bn * NCn * Pn * sizeof(float4));
  float*  sumC           = (float*)alloc((size_t)Bn * NCn * Pn * sizeof(float));
  float2* xe             = (float2*)alloc((size_t)Bn * NCn * Pn * sizeof(float2));
  (void)ws_size; (void)in_sizes; (void)n_in;

  k_prep<<<256, 256, 0, stream>>>(lam_re, lam_im, log_step, b_in, c_in,
                                  lam_bar, b_bfT, c_bfT);
  k_bu_mfma<<<dim3(BTn / BM, NB / BM), 256, 0, stream>>>(inputs, b_bfT, bu);
  k_sum<<<dim3(NCn, Bn), 256, 0, stream>>>((const float2*)bu, mask, lam_bar,
                                           sumAB, sumC);
  k_scan<<<Bn, 256, 0, stream>>>(carry_re, carry_im, sumAB, sumC, xe);
  k_apply_y<<<dim3(NCn, Bn), 256, 0, stream>>>(mask, lam_bar, xe,
                                               (const float2*)bu, c_bfT,
                                               inputs, d_vec, out_y, out_xt,
                                               xt_interleaved);
}